// Round 1
// baseline (193.125 us; speedup 1.0000x reference)
//
#include <hip/hip_runtime.h>
#include <math.h>

// Problem constants (fixed by reference setup_inputs)
#define NS 16            // batch
#define NC 4             // classes
#define HH 256
#define WW 256
#define PIX_PER_N (HH*WW)        // 65536
#define NPIX (NS*PIX_PER_N)      // 1048576 pixels (all classes packed per pixel)
#define CPLANE (PIX_PER_N)       // stride between class planes
#define SAMPLE_STRIDE (NC*PIX_PER_N)

#define RWIN 8
#define T2 81            // (RWIN+1)^2 : windowed result < T2 ==> globally exact
#define FLAG_CAP 4096

// ws layout:
//   [0..8)    double sum_pd
//   [8..16)   double sum_d
//   [16..20)  int flag counter
//   [32..32+4*FLAG_CAP) int flag list
//   [65536 .. 65536+4*NPIX)          uint A  (C-pass result, 4 classes byte-packed)
//   [65536+4*NPIX .. 65536+8*NPIX)   uint B  (H-pass result)

__global__ __launch_bounds__(256) void k_cpass(const int* __restrict__ tgt,
                                               unsigned* __restrict__ A) {
    int idx = blockIdx.x * 256 + threadIdx.x;      // pixel index
    int n = idx >> 16, hw = idx & 65535;
    const int* t = tgt + n * SAMPLE_STRIDE + hw;
    // source (target==1) -> 0, else INF(255)
    int f0 = t[0]          ? 0 : 255;
    int f1 = t[CPLANE]     ? 0 : 255;
    int f2 = t[2*CPLANE]   ? 0 : 255;
    int f3 = t[3*CPLANE]   ? 0 : 255;
    // a[c] = min_{c'} (c-c')^2 + f[c']
    int a0 = min(min(f0,     f1 + 1), min(f2 + 4, f3 + 9));
    int a1 = min(min(f0 + 1, f1    ), min(f2 + 1, f3 + 4));
    int a2 = min(min(f0 + 4, f1 + 1), min(f2,     f3 + 1));
    int a3 = min(min(f0 + 9, f1 + 4), min(f2 + 1, f3    ));
    a0 = min(a0, 255); a1 = min(a1, 255); a2 = min(a2, 255); a3 = min(a3, 255);
    A[idx] = (unsigned)a0 | ((unsigned)a1 << 8) | ((unsigned)a2 << 16) | ((unsigned)a3 << 24);
}

__global__ __launch_bounds__(256) void k_hpass(const unsigned* __restrict__ A,
                                               unsigned* __restrict__ B) {
    int idx = blockIdx.x * 256 + threadIdx.x;
    int n = idx >> 16, h = (idx >> 8) & 255, w = idx & 255;
    const unsigned* An = A + n * PIX_PER_N;
    int v0 = 1023, v1 = 1023, v2 = 1023, v3 = 1023;
#pragma unroll
    for (int dh = -RWIN; dh <= RWIN; ++dh) {
        int hh = h + dh;
        if ((unsigned)hh < (unsigned)HH) {
            unsigned x = An[hh * WW + w];
            int c = dh * dh;
            v0 = min(v0, (int)(x & 255u) + c);
            v1 = min(v1, (int)((x >> 8) & 255u) + c);
            v2 = min(v2, (int)((x >> 16) & 255u) + c);
            v3 = min(v3, (int)(x >> 24) + c);
        }
    }
    v0 = min(v0, 255); v1 = min(v1, 255); v2 = min(v2, 255); v3 = min(v3, 255);
    B[idx] = (unsigned)v0 | ((unsigned)v1 << 8) | ((unsigned)v2 << 16) | ((unsigned)v3 << 24);
}

__global__ __launch_bounds__(256) void k_wpass(const unsigned* __restrict__ B,
                                               const float* __restrict__ pred,
                                               double* __restrict__ sums,
                                               int* __restrict__ counter,
                                               int* __restrict__ list) {
    __shared__ unsigned row[WW];
    __shared__ double wsum[8];
    int bid = blockIdx.x;           // n*256 + h
    int n = bid >> 8, h = bid & 255;
    int w = threadIdx.x;
    row[w] = B[(n << 16) | (h << 8) | w];
    __syncthreads();
    int v0 = 1023, v1 = 1023, v2 = 1023, v3 = 1023;
#pragma unroll
    for (int dw = -RWIN; dw <= RWIN; ++dw) {
        int ww = w + dw;
        if ((unsigned)ww < (unsigned)WW) {
            unsigned x = row[ww];
            int c = dw * dw;
            v0 = min(v0, (int)(x & 255u) + c);
            v1 = min(v1, (int)((x >> 8) & 255u) + c);
            v2 = min(v2, (int)((x >> 16) & 255u) + c);
            v3 = min(v3, (int)(x >> 24) + c);
        }
    }
    int vv[4] = {v0, v1, v2, v3};
    float d[4];
#pragma unroll
    for (int c = 0; c < 4; ++c) {
        if (vv[c] >= T2) {   // windowed result not provably exact -> fallback
            int slot = atomicAdd(counter, 1);
            if (slot < FLAG_CAP) list[slot] = (((n << 2) | c) << 16) | (h << 8) | w;
            d[c] = 0.0f;     // fallback kernel adds this voxel's contribution
        } else {
            d[c] = sqrtf((float)vv[c]);
        }
    }
    const float* P = pred + n * SAMPLE_STRIDE + (h << 8) + w;
    float p0 = P[0], p1 = P[CPLANE], p2 = P[2*CPLANE], p3 = P[3*CPLANE];
    float m = fmaxf(fmaxf(p0, p1), fmaxf(p2, p3));
    float e0 = expf(p0 - m), e1 = expf(p1 - m), e2 = expf(p2 - m), e3 = expf(p3 - m);
    float inv = 1.0f / (e0 + e1 + e2 + e3);
    float pd = (e0 * d[0] + e1 * d[1] + e2 * d[2] + e3 * d[3]) * inv;
    float sd = d[0] + d[1] + d[2] + d[3];
#pragma unroll
    for (int off = 32; off; off >>= 1) {
        pd += __shfl_down(pd, off, 64);
        sd += __shfl_down(sd, off, 64);
    }
    int lane = threadIdx.x & 63, wv = threadIdx.x >> 6;
    if (lane == 0) { wsum[wv] = (double)pd; wsum[4 + wv] = (double)sd; }
    __syncthreads();
    if (threadIdx.x == 0) {
        atomicAdd(&sums[0], wsum[0] + wsum[1] + wsum[2] + wsum[3]);
        atomicAdd(&sums[1], wsum[4] + wsum[5] + wsum[6] + wsum[7]);
    }
}

// Exact brute-force for flagged voxels (normally count == 0).
__global__ __launch_bounds__(256) void k_fallback(const unsigned* __restrict__ A,
                                                  const float* __restrict__ pred,
                                                  double* __restrict__ sums,
                                                  const int* __restrict__ counter,
                                                  const int* __restrict__ list) {
    __shared__ int red[4];
    int cnt = *counter;
    if (cnt > FLAG_CAP) cnt = FLAG_CAP;
    for (int i = 0; i < cnt; ++i) {
        int id = list[i];
        int nc = id >> 16;
        int n = nc >> 2, c = nc & 3;
        int h = (id >> 8) & 255, w = id & 255;
        int best = 0x7FFFFFFF;
        for (int p = threadIdx.x; p < PIX_PER_N; p += 256) {
            unsigned x = A[n * PIX_PER_N + p];
            int ac = (int)((x >> (8 * c)) & 255u);
            if (ac < 255) {
                int dh = (p >> 8) - h, dw = (p & 255) - w;
                best = min(best, dh * dh + dw * dw + ac);
            }
        }
#pragma unroll
        for (int off = 32; off; off >>= 1) best = min(best, __shfl_down(best, off, 64));
        int lane = threadIdx.x & 63, wv = threadIdx.x >> 6;
        if (lane == 0) red[wv] = best;
        __syncthreads();
        if (threadIdx.x == 0) {
            int b = min(min(red[0], red[1]), min(red[2], red[3]));
            float d2 = (b == 0x7FFFFFFF) ? 1e10f : (float)b;   // matches reference INF path
            float dist = sqrtf(d2);
            const float* P = pred + n * SAMPLE_STRIDE + (h << 8) + w;
            float p0 = P[0], p1 = P[CPLANE], p2 = P[2*CPLANE], p3 = P[3*CPLANE];
            float m = fmaxf(fmaxf(p0, p1), fmaxf(p2, p3));
            float e0 = expf(p0 - m), e1 = expf(p1 - m), e2 = expf(p2 - m), e3 = expf(p3 - m);
            float inv = 1.0f / (e0 + e1 + e2 + e3);
            float pc = (c == 0 ? e0 : c == 1 ? e1 : c == 2 ? e2 : e3) * inv;
            atomicAdd(&sums[0], (double)(pc * dist));
            atomicAdd(&sums[1], (double)dist);
        }
        __syncthreads();
    }
}

__global__ void k_final(const double* __restrict__ sums, float* __restrict__ out) {
    out[0] = (float)(sums[0] / (sums[1] + 1e-10));
}

extern "C" void kernel_launch(void* const* d_in, const int* in_sizes, int n_in,
                              void* d_out, int out_size, void* d_ws, size_t ws_size,
                              hipStream_t stream) {
    const float* pred   = (const float*)d_in[0];
    const int*   target = (const int*)d_in[1];
    float* out = (float*)d_out;
    char* ws = (char*)d_ws;

    double* sums   = (double*)ws;
    int*    counter = (int*)(ws + 16);
    int*    list    = (int*)(ws + 32);
    unsigned* A = (unsigned*)(ws + 65536);
    unsigned* B = (unsigned*)(ws + 65536 + 4u * NPIX);

    hipMemsetAsync(ws, 0, 32, stream);                       // zero sums + counter
    k_cpass   <<<NPIX / 256, 256, 0, stream>>>(target, A);
    k_hpass   <<<NPIX / 256, 256, 0, stream>>>(A, B);
    k_wpass   <<<NS * HH,    256, 0, stream>>>(B, pred, sums, counter, list);
    k_fallback<<<1,          256, 0, stream>>>(A, pred, sums, counter, list);
    k_final   <<<1,            1, 0, stream>>>(sums, out);
}

// Round 2
// 114.108 us; speedup vs baseline: 1.6925x; 1.6925x over previous
//
#include <hip/hip_runtime.h>
#include <math.h>

// Problem constants (fixed by reference setup_inputs)
#define NS 16
#define NC 4
#define HH 256
#define WW 256
#define PIX_PER_N (HH*WW)        // 65536
#define CPLANE (PIX_PER_N)
#define SAMPLE_STRIDE (NC*PIX_PER_N)

#define RWIN 8
#define T2 81                    // (RWIN+1)^2 : windowed d2 < T2 ==> globally exact
#define FLAG_CAP 4096

#define TW 64
#define TH 64
#define EX (TW + 2*RWIN)         // 80

// ws layout:
//   [0..16)    double sums[2]  (fallback contributions; zeroed)
//   [16..20)   int flag counter (zeroed)
//   [32..32+4*FLAG_CAP)  int flag list
//   [32768..32768+2*8*256) double partials[256][2]
//   [65536..65536+4*NS*PIX_PER_N) uint A (C-pass result, byte-packed; for fallback)

__global__ __launch_bounds__(256) void k_main(const int* __restrict__ tgt,
                                              const float* __restrict__ pred,
                                              unsigned* __restrict__ gA,
                                              double* __restrict__ partials,
                                              int* __restrict__ counter,
                                              int* __restrict__ list) {
    __shared__ unsigned sA[EX * EX];      // 25.6 KB
    __shared__ unsigned sB[TH * EX];      // 20.5 KB
    __shared__ double wred[8];

    int bid = blockIdx.x;                 // n*16 + ty*4 + tx
    int n  = bid >> 4;
    int h0 = ((bid >> 2) & 3) * TH;
    int w0 = (bid & 3) * TW;
    int tid = threadIdx.x;
    const int* tbase = tgt + n * SAMPLE_STRIDE;

    // Stage 1: C-pass over extended tile (OOB -> 255 = INF)
    for (int i = tid; i < EX * EX; i += 256) {
        int r = i / EX, c = i - r * EX;
        int gh = h0 - RWIN + r, gw = w0 - RWIN + c;
        unsigned pack = 0xFFFFFFFFu;
        if ((unsigned)gh < 256u && (unsigned)gw < 256u) {
            const int* t = tbase + (gh << 8) + gw;
            int f0 = t[0]          ? 0 : 255;
            int f1 = t[CPLANE]     ? 0 : 255;
            int f2 = t[2*CPLANE]   ? 0 : 255;
            int f3 = t[3*CPLANE]   ? 0 : 255;
            int a0 = min(min(f0,     f1 + 1), min(f2 + 4, f3 + 9));
            int a1 = min(min(f0 + 1, f1    ), min(f2 + 1, f3 + 4));
            int a2 = min(min(f0 + 4, f1 + 1), min(f2,     f3 + 1));
            int a3 = min(min(f0 + 9, f1 + 4), min(f2 + 1, f3    ));
            pack = (unsigned)a0 | ((unsigned)a1 << 8) | ((unsigned)a2 << 16) | ((unsigned)a3 << 24);
            if (r >= RWIN && r < RWIN + TH && c >= RWIN && c < RWIN + TW)
                gA[(n << 16) + (gh << 8) + gw] = pack;   // interior only: full coverage, no races
        }
        sA[i] = pack;
    }
    __syncthreads();

    // Stage 2: H-pass (rows windowed) -> sB[64][80]
    for (int i = tid; i < TH * EX; i += 256) {
        int r = i / EX, c = i - r * EX;
        int v0 = 1023, v1 = 1023, v2 = 1023, v3 = 1023;
#pragma unroll
        for (int dh = 0; dh < 17; ++dh) {
            unsigned x = sA[(r + dh) * EX + c];
            int cc = (dh - 8) * (dh - 8);
            v0 = min(v0, (int)(x & 255u) + cc);
            v1 = min(v1, (int)((x >> 8) & 255u) + cc);
            v2 = min(v2, (int)((x >> 16) & 255u) + cc);
            v3 = min(v3, (int)(x >> 24) + cc);
        }
        v0 = min(v0, 255); v1 = min(v1, 255); v2 = min(v2, 255); v3 = min(v3, 255);
        sB[i] = (unsigned)v0 | ((unsigned)v1 << 8) | ((unsigned)v2 << 16) | ((unsigned)v3 << 24);
    }
    __syncthreads();

    // Stage 3: W-pass + softmax + local accumulation
    float accp = 0.0f, accd = 0.0f;
    for (int i = tid; i < TH * TW; i += 256) {
        int r = i >> 6, c = i & 63;
        int v0 = 1023, v1 = 1023, v2 = 1023, v3 = 1023;
#pragma unroll
        for (int dw = 0; dw < 17; ++dw) {
            unsigned x = sB[r * EX + c + dw];
            int cc = (dw - 8) * (dw - 8);
            v0 = min(v0, (int)(x & 255u) + cc);
            v1 = min(v1, (int)((x >> 8) & 255u) + cc);
            v2 = min(v2, (int)((x >> 16) & 255u) + cc);
            v3 = min(v3, (int)(x >> 24) + cc);
        }
        int gh = h0 + r, gw = w0 + c;
        int vv[4] = {v0, v1, v2, v3};
        float d[4];
#pragma unroll
        for (int c4 = 0; c4 < 4; ++c4) {
            if (vv[c4] >= T2) {          // not provably exact -> exact fallback
                int slot = atomicAdd(counter, 1);
                if (slot < FLAG_CAP) list[slot] = (((n << 2) | c4) << 16) | (gh << 8) | gw;
                d[c4] = 0.0f;
            } else {
                d[c4] = sqrtf((float)vv[c4]);
            }
        }
        const float* P = pred + n * SAMPLE_STRIDE + (gh << 8) + gw;
        float p0 = P[0], p1 = P[CPLANE], p2 = P[2*CPLANE], p3 = P[3*CPLANE];
        float m = fmaxf(fmaxf(p0, p1), fmaxf(p2, p3));
        float e0 = expf(p0 - m), e1 = expf(p1 - m), e2 = expf(p2 - m), e3 = expf(p3 - m);
        float inv = 1.0f / (e0 + e1 + e2 + e3);
        accp += (e0 * d[0] + e1 * d[1] + e2 * d[2] + e3 * d[3]) * inv;
        accd += d[0] + d[1] + d[2] + d[3];
    }
#pragma unroll
    for (int off = 32; off; off >>= 1) {
        accp += __shfl_down(accp, off, 64);
        accd += __shfl_down(accd, off, 64);
    }
    int lane = tid & 63, wv = tid >> 6;
    if (lane == 0) { wred[wv] = (double)accp; wred[4 + wv] = (double)accd; }
    __syncthreads();
    if (tid == 0) {
        partials[2 * bid]     = wred[0] + wred[1] + wred[2] + wred[3];
        partials[2 * bid + 1] = wred[4] + wred[5] + wred[6] + wred[7];
    }
}

// Exact brute-force for flagged voxels (normally count == 0).
__global__ __launch_bounds__(256) void k_fallback(const unsigned* __restrict__ A,
                                                  const float* __restrict__ pred,
                                                  double* __restrict__ sums,
                                                  const int* __restrict__ counter,
                                                  const int* __restrict__ list) {
    __shared__ int red[4];
    int cnt = *counter;
    if (cnt > FLAG_CAP) cnt = FLAG_CAP;
    for (int i = 0; i < cnt; ++i) {
        int id = list[i];
        int nc = id >> 16;
        int n = nc >> 2, c = nc & 3;
        int h = (id >> 8) & 255, w = id & 255;
        int best = 0x7FFFFFFF;
        for (int p = threadIdx.x; p < PIX_PER_N; p += 256) {
            unsigned x = A[n * PIX_PER_N + p];
            int ac = (int)((x >> (8 * c)) & 255u);
            if (ac < 255) {
                int dh = (p >> 8) - h, dw = (p & 255) - w;
                best = min(best, dh * dh + dw * dw + ac);
            }
        }
#pragma unroll
        for (int off = 32; off; off >>= 1) best = min(best, __shfl_down(best, off, 64));
        int lane = threadIdx.x & 63, wv = threadIdx.x >> 6;
        if (lane == 0) red[wv] = best;
        __syncthreads();
        if (threadIdx.x == 0) {
            int b = min(min(red[0], red[1]), min(red[2], red[3]));
            float d2 = (b == 0x7FFFFFFF) ? 1e10f : (float)b;
            float dist = sqrtf(d2);
            const float* P = pred + n * SAMPLE_STRIDE + (h << 8) + w;
            float p0 = P[0], p1 = P[CPLANE], p2 = P[2*CPLANE], p3 = P[3*CPLANE];
            float m = fmaxf(fmaxf(p0, p1), fmaxf(p2, p3));
            float e0 = expf(p0 - m), e1 = expf(p1 - m), e2 = expf(p2 - m), e3 = expf(p3 - m);
            float inv = 1.0f / (e0 + e1 + e2 + e3);
            float pc = (c == 0 ? e0 : c == 1 ? e1 : c == 2 ? e2 : e3) * inv;
            atomicAdd(&sums[0], (double)(pc * dist));
            atomicAdd(&sums[1], (double)dist);
        }
        __syncthreads();
    }
}

__global__ __launch_bounds__(256) void k_final(const double* __restrict__ partials,
                                               const double* __restrict__ sums,
                                               float* __restrict__ out) {
    __shared__ double wred[8];
    int t = threadIdx.x;
    double p = partials[2 * t], d = partials[2 * t + 1];
#pragma unroll
    for (int off = 32; off; off >>= 1) {
        p += __shfl_down(p, off, 64);
        d += __shfl_down(d, off, 64);
    }
    int lane = t & 63, wv = t >> 6;
    if (lane == 0) { wred[wv] = p; wred[4 + wv] = d; }
    __syncthreads();
    if (t == 0) {
        double pt = wred[0] + wred[1] + wred[2] + wred[3] + sums[0];
        double dt = wred[4] + wred[5] + wred[6] + wred[7] + sums[1];
        out[0] = (float)(pt / (dt + 1e-10));
    }
}

extern "C" void kernel_launch(void* const* d_in, const int* in_sizes, int n_in,
                              void* d_out, int out_size, void* d_ws, size_t ws_size,
                              hipStream_t stream) {
    const float* pred   = (const float*)d_in[0];
    const int*   target = (const int*)d_in[1];
    float* out = (float*)d_out;
    char* ws = (char*)d_ws;

    double*   sums     = (double*)ws;
    int*      counter  = (int*)(ws + 16);
    int*      list     = (int*)(ws + 32);
    double*   partials = (double*)(ws + 32768);
    unsigned* A        = (unsigned*)(ws + 65536);

    hipMemsetAsync(ws, 0, 32, stream);                 // zero sums + counter
    k_main    <<<NS * 16, 256, 0, stream>>>(target, pred, A, partials, counter, list);
    k_fallback<<<1,       256, 0, stream>>>(A, pred, sums, counter, list);
    k_final   <<<1,       256, 0, stream>>>(partials, sums, out);
}